// Round 5
// baseline (1469.409 us; speedup 1.0000x reference)
//
#include <hip/hip_runtime.h>
#include <hip/hip_bf16.h>

#define NL 4
#define NH 16
#define DM 1024
#define DHD 64
#define NV 32000
#define NB 2
#define NS 2048
#define NM (NB * NS)   // 4096 rows

typedef __attribute__((ext_vector_type(8))) short v8s;   // 8 bf16 (4 VGPRs) MFMA A/B frag
typedef __attribute__((ext_vector_type(4))) float v4f;   // MFMA C/D frag

#define MFMA(a, b, c) __builtin_amdgcn_mfma_f32_16x16x32_bf16(a, b, c, 0, 0, 0)

__device__ __forceinline__ short f2bf(float x) {
    __hip_bfloat16 h = __float2bfloat16(x);   // RNE
    return *reinterpret_cast<short*>(&h);
}
__device__ __forceinline__ float wave_sum(float v) {
    v += __shfl_xor(v, 32); v += __shfl_xor(v, 16); v += __shfl_xor(v, 8);
    v += __shfl_xor(v, 4);  v += __shfl_xor(v, 2);  v += __shfl_xor(v, 1);
    return v;
}
__device__ __forceinline__ float wave_max(float v) {
    v = fmaxf(v, __shfl_xor(v, 32)); v = fmaxf(v, __shfl_xor(v, 16));
    v = fmaxf(v, __shfl_xor(v, 8));  v = fmaxf(v, __shfl_xor(v, 4));
    v = fmaxf(v, __shfl_xor(v, 2));  v = fmaxf(v, __shfl_xor(v, 1));
    return v;
}

// ---------------- one-time weight prep (per call; graph-safe) ----------------
// Wq/Wk/Wv [LH][1024][64] fp32 -> WT bf16 [which*64+lh][64 dh][1024 k]
__global__ __launch_bounds__(256) void wqkv_transpose(
    const float* __restrict__ Wq, const float* __restrict__ Wk,
    const float* __restrict__ Wv, __hip_bfloat16* __restrict__ WT)
{
    __shared__ float T[64][68];
    const int t = threadIdx.x;
    const int k0 = blockIdx.x * 64;
    const int y = blockIdx.y;                 // which*64 + lh
    const int which = y >> 6, lh = y & 63;
    const float* W = (which == 0 ? Wq : which == 1 ? Wk : Wv)
                     + ((size_t)lh * DM + k0) * DHD;
#pragma unroll
    for (int i = 0; i < 4; ++i) {
        const int f = t + i * 256;            // 1024 float4 = 64 k-rows x 16
        const int kr = f >> 4, c = (f & 15) * 4;
        float4 w4 = *(const float4*)&W[(size_t)kr * DHD + c];
        T[kr][c + 0] = w4.x; T[kr][c + 1] = w4.y;
        T[kr][c + 2] = w4.z; T[kr][c + 3] = w4.w;
    }
    __syncthreads();
#pragma unroll
    for (int i = 0; i < 2; ++i) {
        const int f = t + i * 256;            // 512 chunks: 64 n-rows x 8
        const int n = f >> 3, c = (f & 7) * 8;
        short tmp[8];
#pragma unroll
        for (int j = 0; j < 8; ++j) tmp[j] = f2bf(T[c + j][n]);
        *(float4*)&WT[(((size_t)y) * 64 + n) * DM + k0 + c] = *(float4*)tmp;
    }
}

// Wffn [L][1024][1024] fp32 -> WT bf16 [l][1024 n][1024 k]
__global__ __launch_bounds__(256) void wffn_transpose(
    const float* __restrict__ Wffn, __hip_bfloat16* __restrict__ WT)
{
    __shared__ float T[64][68];
    const int t = threadIdx.x;
    const int k0 = blockIdx.x * 64, n0 = blockIdx.y * 64, l = blockIdx.z;
    const float* W = Wffn + ((size_t)l * DM + k0) * DM + n0;
#pragma unroll
    for (int i = 0; i < 4; ++i) {
        const int f = t + i * 256;
        const int kr = f >> 4, c = (f & 15) * 4;
        float4 w4 = *(const float4*)&W[(size_t)kr * DM + c];
        T[kr][c + 0] = w4.x; T[kr][c + 1] = w4.y;
        T[kr][c + 2] = w4.z; T[kr][c + 3] = w4.w;
    }
    __syncthreads();
#pragma unroll
    for (int i = 0; i < 2; ++i) {
        const int f = t + i * 256;
        const int n = f >> 3, c = (f & 7) * 8;
        short tmp[8];
#pragma unroll
        for (int j = 0; j < 8; ++j) tmp[j] = f2bf(T[c + j][n]);
        *(float4*)&WT[((size_t)l * DM + n0 + n) * DM + k0 + c] = *(float4*)tmp;
    }
}

__global__ __launch_bounds__(256) void convert_x0(
    const float* __restrict__ X, __hip_bfloat16* __restrict__ Xh)
{
    const size_t i = ((size_t)blockIdx.x * 256 + threadIdx.x) * 4;
    float4 x = *(const float4*)&X[i];
    union { short s[4]; float2 f2; } hb;
    hb.s[0] = f2bf(x.x); hb.s[1] = f2bf(x.y); hb.s[2] = f2bf(x.z); hb.s[3] = f2bf(x.w);
    *(float2*)&Xh[i] = hb.f2;
}

// ---------------- QKV projection (MFMA, pipelined staging) ----------------
// grid (32, 16): block = 128 rows x 192 cols (q|k|v of head h), K=1024.
// (m,h) remapped so each XCD's resident cell = 8 m-tiles x 8 heads (L2-resident).
// Waves split 2x2: wave = 64 m-rows x 96 n-cols, acc[4][6] -> 20 ds_read_b128
// serve 48 MFMAs per k-step (was rt=2/ct=12: 28 reads) - LDS/MFMA pipes balanced.
// Q/K outputs staged via LDS -> full-line float4 row writes.
__global__ __launch_bounds__(256, 2) void qkv_gemm(
    const __hip_bfloat16* __restrict__ Xh, const __hip_bfloat16* __restrict__ WT,
    const float* __restrict__ bq, const float* __restrict__ bk,
    const float* __restrict__ bv,
    __hip_bfloat16* __restrict__ Q, __hip_bfloat16* __restrict__ K,
    __hip_bfloat16* __restrict__ Vt, int layer)
{
    __shared__ short As[128 * 72];   // X tile [128 m][64 k]; epilogue: Q [128 m][64 dh]
    __shared__ short Bs[192 * 72];   // W^T tile [192 n][64 k]; epilogue: K [128 m][64 dh]
    __shared__ short Vst[64 * 136];  // epilogue: V^T [64 d][128 s]
    const int t = threadIdx.x;
    const int wave = t >> 6, lane = t & 63, l15 = lane & 15, quad = lane >> 4;
    const int wm = wave >> 1, wn = wave & 1;           // 2x2 wave grid
    const int id = blockIdx.y * 32 + blockIdx.x;       // XCD = id % 8
    const int x8 = id & 7, j = id >> 3;
    const int m0 = ((x8 & 3) * 8 + (j & 7)) * 128;     // 8 m-tiles per XCD cell
    const int h = (x8 >> 2) * 8 + (j >> 3);            // 8 heads per XCD cell
    const int lh = layer * NH + h;
    const int arow = t >> 3, ac = (t & 7) * 8;

    v4f acc[4][6];
#pragma unroll
    for (int i = 0; i < 4; ++i)
#pragma unroll
        for (int j2 = 0; j2 < 6; ++j2) acc[i][j2] = 0.f;

    float4 ap[4], bp[6];
#pragma unroll
    for (int i = 0; i < 4; ++i)
        ap[i] = *(const float4*)&Xh[(size_t)(m0 + arow + i * 32) * DM + ac];
#pragma unroll
    for (int i = 0; i < 6; ++i) {
        const int row = arow + i * 32;
        const int which = row >> 6, dh = row & 63;
        bp[i] = *(const float4*)&WT[(((size_t)which * 64 + lh) * 64 + dh) * DM + ac];
    }

    for (int k0 = 0; k0 < DM; k0 += 64) {
        __syncthreads();
#pragma unroll
        for (int i = 0; i < 4; ++i) *(float4*)&As[(arow + i * 32) * 72 + ac] = ap[i];
#pragma unroll
        for (int i = 0; i < 6; ++i) *(float4*)&Bs[(arow + i * 32) * 72 + ac] = bp[i];
        __syncthreads();
        if (k0 + 64 < DM) {                   // prefetch next k-chunk during compute
            const int kn = k0 + 64;
#pragma unroll
            for (int i = 0; i < 4; ++i)
                ap[i] = *(const float4*)&Xh[(size_t)(m0 + arow + i * 32) * DM + kn + ac];
#pragma unroll
            for (int i = 0; i < 6; ++i) {
                const int row = arow + i * 32;
                const int which = row >> 6, dh = row & 63;
                bp[i] = *(const float4*)&WT[(((size_t)which * 64 + lh) * 64 + dh) * DM + kn + ac];
            }
        }

        v8s af[4][2];
#pragma unroll
        for (int rt = 0; rt < 4; ++rt)
#pragma unroll
            for (int kh = 0; kh < 2; ++kh)
                af[rt][kh] = *(const v8s*)&As[(wm * 64 + rt * 16 + l15) * 72 + kh * 32 + quad * 8];
#pragma unroll
        for (int ct = 0; ct < 6; ++ct) {
            v8s b0 = *(const v8s*)&Bs[(wn * 96 + ct * 16 + l15) * 72 + quad * 8];
            v8s b1 = *(const v8s*)&Bs[(wn * 96 + ct * 16 + l15) * 72 + 32 + quad * 8];
#pragma unroll
            for (int rt = 0; rt < 4; ++rt) {
                acc[rt][ct] = MFMA(af[rt][0], b0, acc[rt][ct]);
                acc[rt][ct] = MFMA(af[rt][1], b1, acc[rt][ct]);
            }
        }
    }

    // ---- epilogue: stage Q->As, K->Bs, V^T->Vst; then full-line coalesced writes ----
    __syncthreads();                      // all MFMA frag reads of As/Bs done
#pragma unroll
    for (int ct = 0; ct < 6; ++ct) {
        const int n = wn * 96 + ct * 16 + l15;
        const int which = n >> 6;         // wave-uniform per ct (n>>6 const over l15)
        const int dh = n & 63;
        const float bias = (which == 0 ? bq : which == 1 ? bk : bv)[(size_t)lh * DHD + dh];
#pragma unroll
        for (int rt = 0; rt < 4; ++rt)
#pragma unroll
            for (int r = 0; r < 4; ++r) {
                const int row = wm * 64 + rt * 16 + quad * 4 + r;
                const short val = f2bf(acc[rt][ct][r] + bias);
                if (which == 0)      As[row * 72 + dh] = val;
                else if (which == 1) Bs[row * 72 + dh] = val;
                else                 Vst[dh * 136 + row] = val;
            }
    }
    __syncthreads();
#pragma unroll
    for (int i = 0; i < 4; ++i) {         // Q,K: 128 rows x 8 float4 (full 128-B rows)
        const int f = t + i * 256;
        const int row = f >> 3, c = (f & 7) * 8;
        const int m = m0 + row, bb = m >> 11, s = m & (NS - 1);
        const size_t base = ((size_t)(bb * NH + h) * NS + s) * DHD + c;
        *(float4*)&Q[base] = *(const float4*)&As[row * 72 + c];
        *(float4*)&K[base] = *(const float4*)&Bs[row * 72 + c];
    }
    const int bblk = m0 >> 11;            // block never spans batch (2048 % 128 == 0)
    const int s0 = m0 & (NS - 1);
    const size_t vtb = (size_t)(bblk * NH + h) * DHD * NS;
#pragma unroll
    for (int i = 0; i < 4; ++i) {         // V^T: 64 d-rows x 16 float4
        const int f = t + i * 256;
        const int d = f >> 4, c = (f & 15) * 8;
        *(float4*)&Vt[vtb + (size_t)d * NS + s0 + c] = *(const float4*)&Vst[d * 136 + c];
    }
}

// ---------------- attention (MFMA flash, faithful softmax-then-tril) ----------------
// grid (32 bh, 16 y): block = 128 q rows, 4 waves x 32 rows. Round-2 winner body,
// KVBLK=128: each staging window covers TWO 64-key tiles -> barriers per dispatch
// halved (64 -> 32). Window boundary aligns with causal diagonal (ktd = 2*bi+1):
// pv is window-uniform; tril mask only at wi==bi (dk = sub-tile ts).
// blockIdx.x = bh -> all q-tiles of one (b,h) on ONE XCD (K/V L2-resident).
// bi = (y<8)?y:23-y balances PV work across co-resident pairs.
// FIXED-max softmax (scores O(1)); denominator over ALL tiles (faithful bug).
__global__ __launch_bounds__(256, 2) void attn_kernel(
    const __hip_bfloat16* __restrict__ Q, const __hip_bfloat16* __restrict__ K,
    const __hip_bfloat16* __restrict__ Vt, float* __restrict__ Z)
{
    __shared__ short SMEM[4 * 64 * 72 + 128 * 72];   // K0|K1|V0|V1|Ps; epilogue fp32 Os
    short* Ks0 = SMEM;
    short* Ks1 = SMEM + 4608;
    short* Vs0 = SMEM + 2 * 4608;
    short* Vs1 = SMEM + 3 * 4608;
    short* Ps  = SMEM + 4 * 4608;
    const int t = threadIdx.x;
    const int w = t >> 6, lane = t & 63, l15 = lane & 15, quad = lane >> 4;
    const int bh = blockIdx.x;
    const int y = blockIdx.y;
    const int bi = (y < 8) ? y : (23 - y);           // co-resident pair sums to 15
    const int i0 = bi * 128;
    const int b = bh >> 4, h = bh & 15;
    const size_t qkb = (size_t)bh * NS * DHD;
    const size_t vtb = (size_t)bh * DHD * NS;
    const int arow = t >> 3, ac = (t & 7) * 8;

    // Q fragments for this wave's 32 rows, straight from global (loop-invariant)
    v8s aq[2][2];
#pragma unroll
    for (int rt = 0; rt < 2; ++rt) {
        const size_t qrow = qkb + (size_t)(i0 + w * 32 + rt * 16 + l15) * DHD + quad * 8;
        aq[rt][0] = *(const v8s*)&Q[qrow];
        aq[rt][1] = *(const v8s*)&Q[qrow + 32];
    }

    v4f o[2][4];
    float lpart[2][4];
#pragma unroll
    for (int rt = 0; rt < 2; ++rt)
#pragma unroll
        for (int i = 0; i < 4; ++i) { o[rt][i] = 0.f; lpart[rt][i] = 0.f; }

    float4 kf[4], vf[4];                 // prefetch window 0 (tiles 0,1; always pv)
#pragma unroll
    for (int jj = 0; jj < 2; ++jj)
#pragma unroll
        for (int i = 0; i < 2; ++i) {
            const int row = arow + i * 32;
            kf[jj * 2 + i] = *(const float4*)&K[qkb + (size_t)(jj * 64 + row) * DHD + ac];
            vf[jj * 2 + i] = *(const float4*)&Vt[vtb + (size_t)row * NS + jj * 64 + ac];
        }

    for (int wi = 0; wi < 16; ++wi) {    // NEVER early-exit: l needs full row
        const bool pv = (wi <= bi);      // window-uniform
        __syncthreads();                 // prev window's frag reads done
#pragma unroll
        for (int jj = 0; jj < 2; ++jj)
#pragma unroll
            for (int i = 0; i < 2; ++i) {
                const int row = arow + i * 32;
                *(float4*)&(jj ? Ks1 : Ks0)[row * 72 + ac] = kf[jj * 2 + i];
                if (pv) *(float4*)&(jj ? Vs1 : Vs0)[row * 72 + ac] = vf[jj * 2 + i];
            }
        __syncthreads();                 // window staged
        if (wi < 15) {                   // prefetch next window during compute
            const int n0t = (wi + 1) * 2;
            const bool vneed = (wi + 1 <= bi);
#pragma unroll
            for (int jj = 0; jj < 2; ++jj)
#pragma unroll
                for (int i = 0; i < 2; ++i) {
                    const int row = arow + i * 32;
                    kf[jj * 2 + i] = *(const float4*)&K[qkb + (size_t)((n0t + jj) * 64 + row) * DHD + ac];
                    if (vneed)
                        vf[jj * 2 + i] = *(const float4*)&Vt[vtb + (size_t)row * NS + (n0t + jj) * 64 + ac];
                }
        }

#pragma unroll
        for (int ts = 0; ts < 2; ++ts) { // two 64-key tiles per window
            const short* Ks = ts ? Ks1 : Ks0;
            const short* Vs = ts ? Vs1 : Vs0;

            // QK^T on matrix cores: each K fragment feeds both row-tiles
            v4f s[2][4];
#pragma unroll
            for (int ct = 0; ct < 4; ++ct) {
                v8s b0 = *(const v8s*)&Ks[(ct * 16 + l15) * 72 + quad * 8];
                v8s b1 = *(const v8s*)&Ks[(ct * 16 + l15) * 72 + 32 + quad * 8];
#pragma unroll
                for (int rt = 0; rt < 2; ++rt) {
                    v4f a = 0.f;
                    a = MFMA(aq[rt][0], b0, a);
                    a = MFMA(aq[rt][1], b1, a);
                    s[rt][ct] = a;
                }
            }
            // p = exp(s/8) with fixed max; denominator partials stay per-thread
#pragma unroll
            for (int rt = 0; rt < 2; ++rt) {
#pragma unroll
                for (int ct = 0; ct < 4; ++ct)
#pragma unroll
                    for (int r = 0; r < 4; ++r)
                        s[rt][ct][r] = __expf(s[rt][ct][r] * 0.125f);
#pragma unroll
                for (int r = 0; r < 4; ++r)
                    lpart[rt][r] += s[rt][0][r] + s[rt][1][r] + s[rt][2][r] + s[rt][3][r];
            }

            if (pv) {
                const bool diag = (wi == bi);
#pragma unroll
                for (int rt = 0; rt < 2; ++rt)
#pragma unroll
                    for (int ct = 0; ct < 4; ++ct)
#pragma unroll
                        for (int r = 0; r < 4; ++r) {
                            const int rowl = w * 32 + rt * 16 + quad * 4 + r;  // q in block
                            const int col = ct * 16 + l15;                     // key in tile
                            float pvv = s[rt][ct][r];
                            if (diag && ts * 64 + col > rowl) pvv = 0.f;       // tril mask
                            Ps[rowl * 72 + col] = f2bf(pvv);
                        }
                // wave-private strips: same-wave lgkmcnt ordering, no barrier needed
                v8s ap[2][2];
#pragma unroll
                for (int rt = 0; rt < 2; ++rt) {
                    ap[rt][0] = *(const v8s*)&Ps[(w * 32 + rt * 16 + l15) * 72 + quad * 8];
                    ap[rt][1] = *(const v8s*)&Ps[(w * 32 + rt * 16 + l15) * 72 + 32 + quad * 8];
                }
#pragma unroll
                for (int ct = 0; ct < 4; ++ct) {
                    v8s b0 = *(const v8s*)&Vs[(ct * 16 + l15) * 72 + quad * 8];
                    v8s b1 = *(const v8s*)&Vs[(ct * 16 + l15) * 72 + 32 + quad * 8];
#pragma unroll
                    for (int rt = 0; rt < 2; ++rt) {
                        o[rt][ct] = MFMA(ap[rt][0], b0, o[rt][ct]);
                        o[rt][ct] = MFMA(ap[rt][1], b1, o[rt][ct]);
                    }
                }
            }
        }
    }

    // row denominators: one 16-lane reduction AFTER the loop
#pragma unroll
    for (int m = 1; m < 16; m <<= 1)
#pragma unroll
        for (int rt = 0; rt < 2; ++rt)
#pragma unroll
            for (int r = 0; r < 4; ++r)
                lpart[rt][r] += __shfl_xor(lpart[rt][r], m);

    float* Os = (float*)SMEM;            // [64][68] fp32, two half-passes
#pragma unroll
    for (int half = 0; half < 2; ++half) {
        __syncthreads();                 // previous SMEM reads done
        if ((w >> 1) == half) {          // waves {0,1} -> rows 0..63; {2,3} -> 64..127
#pragma unroll
            for (int rt = 0; rt < 2; ++rt)
#pragma unroll
                for (int r = 0; r < 4; ++r) {
                    const float inv = 1.f / lpart[rt][r];
                    const int row = (w & 1) * 32 + rt * 16 + quad * 4 + r;
#pragma unroll
                    for (int ct = 0; ct < 4; ++ct)
                        Os[row * 68 + ct * 16 + l15] = o[rt][ct][r] * inv;
                }
        }
        __syncthreads();
#pragma unroll
        for (int i = 0; i < 4; ++i) {    // coalesced float4 writes of Z
            const int f = t + i * 256;   // 1024 f4 = 64 rows x 16
            const int row = f >> 4, c4 = (f & 15) * 4;
            float4 v = *(const float4*)&Os[row * 68 + c4];
            *(float4*)&Z[((size_t)b * NS + i0 + half * 64 + row) * DM + h * DHD + c4] = v;
        }
    }
}

// ---------------- FFN GEMM (MFMA, pipelined): R = relu(X @ Wffn + b) ----------------
// grid (64, 8): block = 64 rows x 128 cols, K=1024. Waves split 2x2:
// wave = 32 m x 64 n, acc[2][4] -> 12 ds_read_b128 serve 16 MFMAs per k-step
// (was rt=1/ct=8: 18 reads for 16 MFMAs).
__global__ __launch_bounds__(256, 4) void ffn_gemm(
    const __hip_bfloat16* __restrict__ Xh, const __hip_bfloat16* __restrict__ WT,
    const float* __restrict__ bffn, float* __restrict__ R, int layer)
{
    __shared__ short As[64 * 72];
    __shared__ short Bs[128 * 72];
    const int t = threadIdx.x;
    const int wave = t >> 6, lane = t & 63, l15 = lane & 15, quad = lane >> 4;
    const int wm = wave >> 1, wn = wave & 1;           // 2x2 wave grid
    const int m0 = blockIdx.x * 64, n0 = blockIdx.y * 128;
    const int arow = t >> 3, ac = (t & 7) * 8;

    v4f acc[2][4];
#pragma unroll
    for (int i = 0; i < 2; ++i)
#pragma unroll
        for (int j = 0; j < 4; ++j) acc[i][j] = 0.f;

    float4 ap[2], bp[4];
#pragma unroll
    for (int i = 0; i < 2; ++i)
        ap[i] = *(const float4*)&Xh[(size_t)(m0 + arow + i * 32) * DM + ac];
#pragma unroll
    for (int i = 0; i < 4; ++i)
        bp[i] = *(const float4*)&WT[((size_t)layer * DM + n0 + arow + i * 32) * DM + ac];

    for (int k0 = 0; k0 < DM; k0 += 64) {
        __syncthreads();
#pragma unroll
        for (int i = 0; i < 2; ++i) *(float4*)&As[(arow + i * 32) * 72 + ac] = ap[i];
#pragma unroll
        for (int i = 0; i < 4; ++i) *(float4*)&Bs[(arow + i * 32) * 72 + ac] = bp[i];
        __syncthreads();
        if (k0 + 64 < DM) {
            const int kn = k0 + 64;
#pragma unroll
            for (int i = 0; i < 2; ++i)
                ap[i] = *(const float4*)&Xh[(size_t)(m0 + arow + i * 32) * DM + kn + ac];
#pragma unroll
            for (int i = 0; i < 4; ++i)
                bp[i] = *(const float4*)&WT[((size_t)layer * DM + n0 + arow + i * 32) * DM + kn + ac];
        }

        v8s af[2][2];
#pragma unroll
        for (int rt = 0; rt < 2; ++rt)
#pragma unroll
            for (int kh = 0; kh < 2; ++kh)
                af[rt][kh] = *(const v8s*)&As[(wm * 32 + rt * 16 + l15) * 72 + kh * 32 + quad * 8];
#pragma unroll
        for (int ct = 0; ct < 4; ++ct) {
            v8s b0 = *(const v8s*)&Bs[(wn * 64 + ct * 16 + l15) * 72 + quad * 8];
            v8s b1 = *(const v8s*)&Bs[(wn * 64 + ct * 16 + l15) * 72 + 32 + quad * 8];
#pragma unroll
            for (int rt = 0; rt < 2; ++rt) {
                acc[rt][ct] = MFMA(af[rt][0], b0, acc[rt][ct]);
                acc[rt][ct] = MFMA(af[rt][1], b1, acc[rt][ct]);
            }
        }
    }
#pragma unroll
    for (int ct = 0; ct < 4; ++ct) {
        const int n = n0 + wn * 64 + ct * 16 + l15;
        const float bias = bffn[(size_t)layer * DM + n];
#pragma unroll
        for (int rt = 0; rt < 2; ++rt)
#pragma unroll
            for (int r = 0; r < 4; ++r) {
                const int m = m0 + wm * 32 + rt * 16 + quad * 4 + r;
                R[(size_t)m * DM + n] = fmaxf(acc[rt][ct][r] + bias, 0.f);
            }
    }
}

// ---------------- X = (X+R - mu) / var  (divide by VARIANCE — faithful bug) ----------------
__global__ __launch_bounds__(256) void add_ln(
    const float* __restrict__ Xin, const float* __restrict__ Rr,
    float* __restrict__ Xout, __hip_bfloat16* __restrict__ Xh)
{
    __shared__ float red[8];
    const int t = threadIdx.x;
    const size_t base = (size_t)blockIdx.x * DM;
    float4 x4 = *(const float4*)&Xin[base + t * 4];
    float4 r4 = *(const float4*)&Rr[base + t * 4];
    float v[4] = {x4.x + r4.x, x4.y + r4.y, x4.z + r4.z, x4.w + r4.w};
    float ssum = wave_sum(v[0] + v[1] + v[2] + v[3]);
    if ((t & 63) == 0) red[t >> 6] = ssum;
    __syncthreads();
    const float mu = (red[0] + red[1] + red[2] + red[3]) * (1.f / DM);
    float sq = 0.f;
#pragma unroll
    for (int i = 0; i < 4; ++i) { const float d = v[i] - mu; sq = fmaf(d, d, sq); }
    sq = wave_sum(sq);
    if ((t & 63) == 0) red[4 + (t >> 6)] = sq;
    __syncthreads();
    const float var = (red[4] + red[5] + red[6] + red[7]) * (1.f / DM);
    const float inv = 1.f / var;
    float4 o = {(v[0] - mu) * inv, (v[1] - mu) * inv, (v[2] - mu) * inv, (v[3] - mu) * inv};
    *(float4*)&Xout[base + t * 4] = o;
    union { short s[4]; float2 f2; } hb;
    hb.s[0] = f2bf(o.x); hb.s[1] = f2bf(o.y); hb.s[2] = f2bf(o.z); hb.s[3] = f2bf(o.w);
    *(float2*)&Xh[base + t * 4] = hb.f2;
}

// ---------------- last-token logits, both batches in one pass over Wout ----------------
__global__ __launch_bounds__(256) void last_logits2(
    const float* __restrict__ X, const float* __restrict__ Wout,
    const float* __restrict__ bout, float* __restrict__ logits)
{
    __shared__ float xs[2 * DM];
    const int t = threadIdx.x;
    for (int k = t; k < 2 * DM; k += 256) {
        const int bb = k >> 10, d = k & (DM - 1);
        xs[k] = X[((size_t)bb * NS + NS - 1) * DM + d];
    }
    __syncthreads();
    const int v = blockIdx.x * 256 + t;
    float a0 = bout[v], a1 = a0;
    for (int d = 0; d < DM; ++d) {
        const float w = Wout[(size_t)d * NV + v];   // coalesced; Wout read ONCE
        a0 = fmaf(xs[d], w, a0);
        a1 = fmaf(xs[DM + d], w, a1);
    }
    logits[v] = a0;
    logits[NV + v] = a1;
}

__global__ __launch_bounds__(256) void final_softmax(
    const float* __restrict__ logits, float* __restrict__ out)
{
    __shared__ float red[8];
    const int b = blockIdx.x, t = threadIdx.x;
    const float* lp = logits + b * NV;
    float mx = -1e30f;
    for (int v = t; v < NV; v += 256) mx = fmaxf(mx, lp[v]);
    mx = wave_max(mx);
    if ((t & 63) == 0) red[t >> 6] = mx;
    __syncthreads();
    mx = fmaxf(fmaxf(red[0], red[1]), fmaxf(red[2], red[3]));
    float sum = 0.f;
    for (int v = t; v < NV; v += 256) sum += __expf(lp[v] - mx);
    sum = wave_sum(sum);
    if ((t & 63) == 0) red[4 + (t >> 6)] = sum;
    __syncthreads();
    sum = red[4] + red[5] + red[6] + red[7];
    const float inv = 1.f / sum;
    for (int v = t; v < NV; v += 256) out[b * NV + v] = __expf(lp[v] - mx) * inv;
}

extern "C" void kernel_launch(void* const* d_in, const int* in_sizes, int n_in,
                              void* d_out, int out_size, void* d_ws, size_t ws_size,
                              hipStream_t stream)
{
    (void)in_sizes; (void)n_in; (void)out_size; (void)ws_size;
    const float* X_in = (const float*)d_in[0];
    const float* Wq   = (const float*)d_in[1];
    const float* Wk   = (const float*)d_in[2];
    const float* Wv   = (const float*)d_in[3];
    const float* bq   = (const float*)d_in[4];
    const float* bk   = (const float*)d_in[5];
    const float* bv   = (const float*)d_in[6];
    const float* Wffn = (const float*)d_in[7];
    const float* bffn = (const float*)d_in[8];
    const float* Wout = (const float*)d_in[9];
    const float* bout = (const float*)d_in[10];
    float* out = (float*)d_out;

    // workspace carve-up (~101 MB)
    const size_t NE = (size_t)NM * DM;
    char* p = (char*)d_ws;
    float* Xb = (float*)p;                    p += NE * 4;
    float* Rb = (float*)p;                    p += NE * 4;
    float* logits = (float*)p;                p += (size_t)NB * NV * 4;
    __hip_bfloat16* Xhi  = (__hip_bfloat16*)p; p += NE * 2;
    __hip_bfloat16* Qb   = (__hip_bfloat16*)p; p += NE * 2;
    __hip_bfloat16* Kb   = (__hip_bfloat16*)p; p += NE * 2;
    __hip_bfloat16* Vtb  = (__hip_bfloat16*)p; p += NE * 2;
    __hip_bfloat16* WqkvT = (__hip_bfloat16*)p; p += (size_t)3 * 64 * 64 * DM * 2;
    __hip_bfloat16* WffnT = (__hip_bfloat16*)p; p += (size_t)NL * DM * DM * 2;

    wqkv_transpose<<<dim3(16, 192), 256, 0, stream>>>(Wq, Wk, Wv, WqkvT);
    wffn_transpose<<<dim3(16, 16, NL), 256, 0, stream>>>(Wffn, WffnT);
    convert_x0<<<NM, 256, 0, stream>>>(X_in, Xhi);

    for (int l = 0; l < NL; ++l) {
        const float* Xcur = (l == 0) ? X_in : Xb;   // never write d_in
        qkv_gemm<<<dim3(32, 16), 256, 0, stream>>>(Xhi, WqkvT, bq, bk, bv, Qb, Kb, Vtb, l);
        attn_kernel<<<dim3(32, 16), 256, 0, stream>>>(Qb, Kb, Vtb, Rb);
        add_ln<<<NM, 256, 0, stream>>>(Xcur, Rb, Xb, Xhi);
        ffn_gemm<<<dim3(64, 8), 256, 0, stream>>>(Xhi, WffnT, bffn, Rb, l);
        add_ln<<<NM, 256, 0, stream>>>(Xb, Rb, Xb, Xhi);
    }
    last_logits2<<<NV / 256, 256, 0, stream>>>(Xb, Wout, bout, logits);
    final_softmax<<<NB, 256, 0, stream>>>(logits, out);
}

// Round 6
// 1248.823 us; speedup vs baseline: 1.1766x; 1.1766x over previous
//
#include <hip/hip_runtime.h>
#include <hip/hip_bf16.h>

#define NL 4
#define NH 16
#define DM 1024
#define DHD 64
#define NV 32000
#define NB 2
#define NS 2048
#define NM (NB * NS)   // 4096 rows

typedef __attribute__((ext_vector_type(8))) short v8s;   // 8 bf16 (4 VGPRs) MFMA A/B frag
typedef __attribute__((ext_vector_type(4))) float v4f;   // MFMA C/D frag

#define MFMA(a, b, c) __builtin_amdgcn_mfma_f32_16x16x32_bf16(a, b, c, 0, 0, 0)

__device__ __forceinline__ short f2bf(float x) {
    __hip_bfloat16 h = __float2bfloat16(x);   // RNE
    return *reinterpret_cast<short*>(&h);
}
__device__ __forceinline__ float wave_sum(float v) {
    v += __shfl_xor(v, 32); v += __shfl_xor(v, 16); v += __shfl_xor(v, 8);
    v += __shfl_xor(v, 4);  v += __shfl_xor(v, 2);  v += __shfl_xor(v, 1);
    return v;
}
__device__ __forceinline__ float wave_max(float v) {
    v = fmaxf(v, __shfl_xor(v, 32)); v = fmaxf(v, __shfl_xor(v, 16));
    v = fmaxf(v, __shfl_xor(v, 8));  v = fmaxf(v, __shfl_xor(v, 4));
    v = fmaxf(v, __shfl_xor(v, 2));  v = fmaxf(v, __shfl_xor(v, 1));
    return v;
}

// ---------------- one-time weight prep (per call; graph-safe) ----------------
// Wq/Wk/Wv [LH][1024][64] fp32 -> WT bf16 [which*64+lh][64 dh][1024 k]
__global__ __launch_bounds__(256) void wqkv_transpose(
    const float* __restrict__ Wq, const float* __restrict__ Wk,
    const float* __restrict__ Wv, __hip_bfloat16* __restrict__ WT)
{
    __shared__ float T[64][68];
    const int t = threadIdx.x;
    const int k0 = blockIdx.x * 64;
    const int y = blockIdx.y;                 // which*64 + lh
    const int which = y >> 6, lh = y & 63;
    const float* W = (which == 0 ? Wq : which == 1 ? Wk : Wv)
                     + ((size_t)lh * DM + k0) * DHD;
#pragma unroll
    for (int i = 0; i < 4; ++i) {
        const int f = t + i * 256;            // 1024 float4 = 64 k-rows x 16
        const int kr = f >> 4, c = (f & 15) * 4;
        float4 w4 = *(const float4*)&W[(size_t)kr * DHD + c];
        T[kr][c + 0] = w4.x; T[kr][c + 1] = w4.y;
        T[kr][c + 2] = w4.z; T[kr][c + 3] = w4.w;
    }
    __syncthreads();
#pragma unroll
    for (int i = 0; i < 2; ++i) {
        const int f = t + i * 256;            // 512 chunks: 64 n-rows x 8
        const int n = f >> 3, c = (f & 7) * 8;
        short tmp[8];
#pragma unroll
        for (int j = 0; j < 8; ++j) tmp[j] = f2bf(T[c + j][n]);
        *(float4*)&WT[(((size_t)y) * 64 + n) * DM + k0 + c] = *(float4*)tmp;
    }
}

// Wffn [L][1024][1024] fp32 -> WT bf16 [l][1024 n][1024 k]
__global__ __launch_bounds__(256) void wffn_transpose(
    const float* __restrict__ Wffn, __hip_bfloat16* __restrict__ WT)
{
    __shared__ float T[64][68];
    const int t = threadIdx.x;
    const int k0 = blockIdx.x * 64, n0 = blockIdx.y * 64, l = blockIdx.z;
    const float* W = Wffn + ((size_t)l * DM + k0) * DM + n0;
#pragma unroll
    for (int i = 0; i < 4; ++i) {
        const int f = t + i * 256;
        const int kr = f >> 4, c = (f & 15) * 4;
        float4 w4 = *(const float4*)&W[(size_t)kr * DM + c];
        T[kr][c + 0] = w4.x; T[kr][c + 1] = w4.y;
        T[kr][c + 2] = w4.z; T[kr][c + 3] = w4.w;
    }
    __syncthreads();
#pragma unroll
    for (int i = 0; i < 2; ++i) {
        const int f = t + i * 256;
        const int n = f >> 3, c = (f & 7) * 8;
        short tmp[8];
#pragma unroll
        for (int j = 0; j < 8; ++j) tmp[j] = f2bf(T[c + j][n]);
        *(float4*)&WT[((size_t)l * DM + n0 + n) * DM + k0 + c] = *(float4*)tmp;
    }
}

__global__ __launch_bounds__(256) void convert_x0(
    const float* __restrict__ X, __hip_bfloat16* __restrict__ Xh)
{
    const size_t i = ((size_t)blockIdx.x * 256 + threadIdx.x) * 4;
    float4 x = *(const float4*)&X[i];
    union { short s[4]; float2 f2; } hb;
    hb.s[0] = f2bf(x.x); hb.s[1] = f2bf(x.y); hb.s[2] = f2bf(x.z); hb.s[3] = f2bf(x.w);
    *(float2*)&Xh[i] = hb.f2;
}

// ---------------- QKV projection (MFMA, pipelined staging) ----------------
// grid (32, 16): block = 128 rows x 192 cols (q|k|v of head h), K=1024.
// (m,h) remapped so each XCD's resident cell = 8 m-tiles x 8 heads (L2-resident).
// Waves split 2x2: wave = 64 m-rows x 96 n-cols, acc[4][6] -> 20 ds_read_b128
// serve 48 MFMAs per k-step - LDS/MFMA pipes balanced.
// Q/K outputs staged via LDS -> full-line float4 row writes.
__global__ __launch_bounds__(256, 2) void qkv_gemm(
    const __hip_bfloat16* __restrict__ Xh, const __hip_bfloat16* __restrict__ WT,
    const float* __restrict__ bq, const float* __restrict__ bk,
    const float* __restrict__ bv,
    __hip_bfloat16* __restrict__ Q, __hip_bfloat16* __restrict__ K,
    __hip_bfloat16* __restrict__ Vt, int layer)
{
    __shared__ short As[128 * 72];   // X tile [128 m][64 k]; epilogue: Q [128 m][64 dh]
    __shared__ short Bs[192 * 72];   // W^T tile [192 n][64 k]; epilogue: K [128 m][64 dh]
    __shared__ short Vst[64 * 136];  // epilogue: V^T [64 d][128 s]
    const int t = threadIdx.x;
    const int wave = t >> 6, lane = t & 63, l15 = lane & 15, quad = lane >> 4;
    const int wm = wave >> 1, wn = wave & 1;           // 2x2 wave grid
    const int id = blockIdx.y * 32 + blockIdx.x;       // XCD = id % 8
    const int x8 = id & 7, j = id >> 3;
    const int m0 = ((x8 & 3) * 8 + (j & 7)) * 128;     // 8 m-tiles per XCD cell
    const int h = (x8 >> 2) * 8 + (j >> 3);            // 8 heads per XCD cell
    const int lh = layer * NH + h;
    const int arow = t >> 3, ac = (t & 7) * 8;

    v4f acc[4][6];
#pragma unroll
    for (int i = 0; i < 4; ++i)
#pragma unroll
        for (int j2 = 0; j2 < 6; ++j2) acc[i][j2] = 0.f;

    float4 ap[4], bp[6];
#pragma unroll
    for (int i = 0; i < 4; ++i)
        ap[i] = *(const float4*)&Xh[(size_t)(m0 + arow + i * 32) * DM + ac];
#pragma unroll
    for (int i = 0; i < 6; ++i) {
        const int row = arow + i * 32;
        const int which = row >> 6, dh = row & 63;
        bp[i] = *(const float4*)&WT[(((size_t)which * 64 + lh) * 64 + dh) * DM + ac];
    }

    for (int k0 = 0; k0 < DM; k0 += 64) {
        __syncthreads();
#pragma unroll
        for (int i = 0; i < 4; ++i) *(float4*)&As[(arow + i * 32) * 72 + ac] = ap[i];
#pragma unroll
        for (int i = 0; i < 6; ++i) *(float4*)&Bs[(arow + i * 32) * 72 + ac] = bp[i];
        __syncthreads();
        if (k0 + 64 < DM) {                   // prefetch next k-chunk during compute
            const int kn = k0 + 64;
#pragma unroll
            for (int i = 0; i < 4; ++i)
                ap[i] = *(const float4*)&Xh[(size_t)(m0 + arow + i * 32) * DM + kn + ac];
#pragma unroll
            for (int i = 0; i < 6; ++i) {
                const int row = arow + i * 32;
                const int which = row >> 6, dh = row & 63;
                bp[i] = *(const float4*)&WT[(((size_t)which * 64 + lh) * 64 + dh) * DM + kn + ac];
            }
        }

        v8s af[4][2];
#pragma unroll
        for (int rt = 0; rt < 4; ++rt)
#pragma unroll
            for (int kh = 0; kh < 2; ++kh)
                af[rt][kh] = *(const v8s*)&As[(wm * 64 + rt * 16 + l15) * 72 + kh * 32 + quad * 8];
#pragma unroll
        for (int ct = 0; ct < 6; ++ct) {
            v8s b0 = *(const v8s*)&Bs[(wn * 96 + ct * 16 + l15) * 72 + quad * 8];
            v8s b1 = *(const v8s*)&Bs[(wn * 96 + ct * 16 + l15) * 72 + 32 + quad * 8];
#pragma unroll
            for (int rt = 0; rt < 4; ++rt) {
                acc[rt][ct] = MFMA(af[rt][0], b0, acc[rt][ct]);
                acc[rt][ct] = MFMA(af[rt][1], b1, acc[rt][ct]);
            }
        }
    }

    // ---- epilogue: stage Q->As, K->Bs, V^T->Vst; then full-line coalesced writes ----
    __syncthreads();                      // all MFMA frag reads of As/Bs done
#pragma unroll
    for (int ct = 0; ct < 6; ++ct) {
        const int n = wn * 96 + ct * 16 + l15;
        const int which = n >> 6;         // wave-uniform per ct (n>>6 const over l15)
        const int dh = n & 63;
        const float bias = (which == 0 ? bq : which == 1 ? bk : bv)[(size_t)lh * DHD + dh];
#pragma unroll
        for (int rt = 0; rt < 4; ++rt)
#pragma unroll
            for (int r = 0; r < 4; ++r) {
                const int row = wm * 64 + rt * 16 + quad * 4 + r;
                const short val = f2bf(acc[rt][ct][r] + bias);
                if (which == 0)      As[row * 72 + dh] = val;
                else if (which == 1) Bs[row * 72 + dh] = val;
                else                 Vst[dh * 136 + row] = val;
            }
    }
    __syncthreads();
#pragma unroll
    for (int i = 0; i < 4; ++i) {         // Q,K: 128 rows x 8 float4 (full 128-B rows)
        const int f = t + i * 256;
        const int row = f >> 3, c = (f & 7) * 8;
        const int m = m0 + row, bb = m >> 11, s = m & (NS - 1);
        const size_t base = ((size_t)(bb * NH + h) * NS + s) * DHD + c;
        *(float4*)&Q[base] = *(const float4*)&As[row * 72 + c];
        *(float4*)&K[base] = *(const float4*)&Bs[row * 72 + c];
    }
    const int bblk = m0 >> 11;            // block never spans batch (2048 % 128 == 0)
    const int s0 = m0 & (NS - 1);
    const size_t vtb = (size_t)(bblk * NH + h) * DHD * NS;
#pragma unroll
    for (int i = 0; i < 4; ++i) {         // V^T: 64 d-rows x 16 float4
        const int f = t + i * 256;
        const int d = f >> 4, c = (f & 15) * 8;
        *(float4*)&Vt[vtb + (size_t)d * NS + s0 + c] = *(const float4*)&Vst[d * 136 + c];
    }
}

// ---------------- attention (MFMA flash, faithful softmax-then-tril) ----------------
// grid (32 bh, 16 y): block = 512 threads, 8 waves x 16 q-rows = 128-row q tile.
// Round-6 geometry: keeps round-2's staging amortization (ONE float4/thread/tile;
// one stage serves 8 waves) but doubles TLP: 512 blocks x 8 waves = 16 waves/CU
// (4/SIMD) vs round-2's 8 (2/SIMD). The per-tile serial chain (QK MFMA -> exp ->
// P LDS round-trip -> PV MFMA) is latency-bound; 4 wave-contexts/SIMD hide it.
// blockIdx.x = bh -> all q-tiles of one (b,h) on ONE XCD (K/V L2-resident).
// bi = (y<8)?y:23-y balances PV work across co-resident pairs.
// FIXED-max softmax (scores O(1)); denominator over ALL tiles (faithful bug);
// tril masks P only; PV (and V loads/stages) skipped for fully-masked tiles.
__global__ __launch_bounds__(512, 4) void attn_kernel(
    const __hip_bfloat16* __restrict__ Q, const __hip_bfloat16* __restrict__ K,
    const __hip_bfloat16* __restrict__ Vt, float* __restrict__ Z)
{
    __shared__ short SMEM[2 * 64 * 72 + 128 * 72];   // Ks | Vs | Ps ; epilogue fp32 Os[64][68]
    short* Ks = SMEM;
    short* Vs = SMEM + 64 * 72;
    short* Ps = SMEM + 2 * 64 * 72;
    const int t = threadIdx.x;                       // 0..511
    const int w = t >> 6, lane = t & 63, l15 = lane & 15, quad = lane >> 4;
    const int bh = blockIdx.x;
    const int y = blockIdx.y;
    const int bi = (y < 8) ? y : (23 - y);           // co-resident pair sums to 15
    const int i0 = bi * 128;
    const int b = bh >> 4, h = bh & 15;
    const size_t qkb = (size_t)bh * NS * DHD;
    const size_t vtb = (size_t)bh * DHD * NS;
    const int arow = t >> 3, ac = (t & 7) * 8;       // arow 0..63: 1 float4/thread
    const int r0 = w * 16;                           // wave's q-row offset in tile
    const int ktd = 2 * bi + 1;                      // last key tile with PV

    // Q fragments for this wave's 16 rows, straight from global (loop-invariant)
    const size_t qrow = qkb + (size_t)(i0 + r0 + l15) * DHD + quad * 8;
    const v8s aq0 = *(const v8s*)&Q[qrow];
    const v8s aq1 = *(const v8s*)&Q[qrow + 32];

    v4f o[4];
    float lpart[4] = {0.f, 0.f, 0.f, 0.f};
#pragma unroll
    for (int i = 0; i < 4; ++i) o[i] = 0.f;

    float4 kf, vf;                       // prefetch tile 0 (always pv)
    kf = *(const float4*)&K[qkb + (size_t)arow * DHD + ac];
    vf = *(const float4*)&Vt[vtb + (size_t)arow * NS + ac];

    for (int kt = 0; kt < 32; ++kt) {    // NEVER early-exit: l needs full row
        const bool pv = (kt <= ktd);     // block-uniform
        __syncthreads();                 // prev tile's frag reads done
        *(float4*)&Ks[arow * 72 + ac] = kf;
        if (pv) *(float4*)&Vs[arow * 72 + ac] = vf;
        __syncthreads();                 // tile staged
        if (kt < 31) {                   // prefetch next tile during compute
            const int nt = kt + 1;
            kf = *(const float4*)&K[qkb + (size_t)(nt * 64 + arow) * DHD + ac];
            if (nt <= ktd)               // V only needed for unmasked tiles
                vf = *(const float4*)&Vt[vtb + (size_t)arow * NS + nt * 64 + ac];
        }

        // QK^T on matrix cores
        v4f s[4];
#pragma unroll
        for (int ct = 0; ct < 4; ++ct) {
            v8s b0 = *(const v8s*)&Ks[(ct * 16 + l15) * 72 + quad * 8];
            v8s b1 = *(const v8s*)&Ks[(ct * 16 + l15) * 72 + 32 + quad * 8];
            v4f a = 0.f;
            a = MFMA(aq0, b0, a);
            a = MFMA(aq1, b1, a);
            s[ct] = a;
        }
        // p = exp(s/8) with fixed max; denominator partials stay per-thread
#pragma unroll
        for (int ct = 0; ct < 4; ++ct)
#pragma unroll
            for (int r = 0; r < 4; ++r)
                s[ct][r] = __expf(s[ct][r] * 0.125f);
#pragma unroll
        for (int r = 0; r < 4; ++r)
            lpart[r] += s[0][r] + s[1][r] + s[2][r] + s[3][r];

        if (pv) {
            const int dk = kt - 2 * bi;  // 0/1 on diagonal tiles, negative before
#pragma unroll
            for (int ct = 0; ct < 4; ++ct)
#pragma unroll
                for (int r = 0; r < 4; ++r) {
                    const int rowl = r0 + quad * 4 + r;     // q index in 128-row tile
                    const int col = ct * 16 + l15;          // key index in tile
                    float pvv = s[ct][r];
                    if (dk >= 0 && dk * 64 + col > rowl) pvv = 0.f;  // tril mask
                    Ps[rowl * 72 + col] = f2bf(pvv);
                }
            // wave-private strip: same-wave lgkmcnt ordering, no barrier needed
            v8s ap0 = *(const v8s*)&Ps[(r0 + l15) * 72 + quad * 8];
            v8s ap1 = *(const v8s*)&Ps[(r0 + l15) * 72 + 32 + quad * 8];
#pragma unroll
            for (int ct = 0; ct < 4; ++ct) {
                v8s b0 = *(const v8s*)&Vs[(ct * 16 + l15) * 72 + quad * 8];
                v8s b1 = *(const v8s*)&Vs[(ct * 16 + l15) * 72 + 32 + quad * 8];
                o[ct] = MFMA(ap0, b0, o[ct]);
                o[ct] = MFMA(ap1, b1, o[ct]);
            }
        }
    }

    // row denominators: one 16-lane reduction AFTER the loop
#pragma unroll
    for (int m = 1; m < 16; m <<= 1)
#pragma unroll
        for (int r = 0; r < 4; ++r) lpart[r] += __shfl_xor(lpart[r], m);

    float* Os = (float*)SMEM;            // [64][68] fp32, two half-passes
#pragma unroll
    for (int half = 0; half < 2; ++half) {
        __syncthreads();                 // previous SMEM reads done
        if ((w >> 2) == half) {          // waves 0-3 -> rows 0..63; 4-7 -> 64..127
#pragma unroll
            for (int r = 0; r < 4; ++r) {
                const float inv = 1.f / lpart[r];
                const int row = (w & 3) * 16 + quad * 4 + r;
#pragma unroll
                for (int ct = 0; ct < 4; ++ct)
                    Os[row * 68 + ct * 16 + l15] = o[ct][r] * inv;
            }
        }
        __syncthreads();
#pragma unroll
        for (int i = 0; i < 2; ++i) {    // coalesced float4 writes of Z
            const int f = t + i * 512;   // 1024 f4 = 64 rows x 16
            const int row = f >> 4, c4 = (f & 15) * 4;
            float4 v = *(const float4*)&Os[row * 68 + c4];
            *(float4*)&Z[((size_t)b * NS + i0 + half * 64 + row) * DM + h * DHD + c4] = v;
        }
    }
}

// ---------------- FFN GEMM (MFMA, pipelined): R = relu(X @ Wffn + b) ----------------
// grid (64, 8): block = 64 rows x 128 cols, K=1024. Waves split 2x2:
// wave = 32 m x 64 n, acc[2][4] -> 12 ds_read_b128 serve 16 MFMAs per k-step.
__global__ __launch_bounds__(256, 4) void ffn_gemm(
    const __hip_bfloat16* __restrict__ Xh, const __hip_bfloat16* __restrict__ WT,
    const float* __restrict__ bffn, float* __restrict__ R, int layer)
{
    __shared__ short As[64 * 72];
    __shared__ short Bs[128 * 72];
    const int t = threadIdx.x;
    const int wave = t >> 6, lane = t & 63, l15 = lane & 15, quad = lane >> 4;
    const int wm = wave >> 1, wn = wave & 1;           // 2x2 wave grid
    const int m0 = blockIdx.x * 64, n0 = blockIdx.y * 128;
    const int arow = t >> 3, ac = (t & 7) * 8;

    v4f acc[2][4];
#pragma unroll
    for (int i = 0; i < 2; ++i)
#pragma unroll
        for (int j = 0; j < 4; ++j) acc[i][j] = 0.f;

    float4 ap[2], bp[4];
#pragma unroll
    for (int i = 0; i < 2; ++i)
        ap[i] = *(const float4*)&Xh[(size_t)(m0 + arow + i * 32) * DM + ac];
#pragma unroll
    for (int i = 0; i < 4; ++i)
        bp[i] = *(const float4*)&WT[((size_t)layer * DM + n0 + arow + i * 32) * DM + ac];

    for (int k0 = 0; k0 < DM; k0 += 64) {
        __syncthreads();
#pragma unroll
        for (int i = 0; i < 2; ++i) *(float4*)&As[(arow + i * 32) * 72 + ac] = ap[i];
#pragma unroll
        for (int i = 0; i < 4; ++i) *(float4*)&Bs[(arow + i * 32) * 72 + ac] = bp[i];
        __syncthreads();
        if (k0 + 64 < DM) {
            const int kn = k0 + 64;
#pragma unroll
            for (int i = 0; i < 2; ++i)
                ap[i] = *(const float4*)&Xh[(size_t)(m0 + arow + i * 32) * DM + kn + ac];
#pragma unroll
            for (int i = 0; i < 4; ++i)
                bp[i] = *(const float4*)&WT[((size_t)layer * DM + n0 + arow + i * 32) * DM + kn + ac];
        }

        v8s af[2][2];
#pragma unroll
        for (int rt = 0; rt < 2; ++rt)
#pragma unroll
            for (int kh = 0; kh < 2; ++kh)
                af[rt][kh] = *(const v8s*)&As[(wm * 32 + rt * 16 + l15) * 72 + kh * 32 + quad * 8];
#pragma unroll
        for (int ct = 0; ct < 4; ++ct) {
            v8s b0 = *(const v8s*)&Bs[(wn * 64 + ct * 16 + l15) * 72 + quad * 8];
            v8s b1 = *(const v8s*)&Bs[(wn * 64 + ct * 16 + l15) * 72 + 32 + quad * 8];
#pragma unroll
            for (int rt = 0; rt < 2; ++rt) {
                acc[rt][ct] = MFMA(af[rt][0], b0, acc[rt][ct]);
                acc[rt][ct] = MFMA(af[rt][1], b1, acc[rt][ct]);
            }
        }
    }
#pragma unroll
    for (int ct = 0; ct < 4; ++ct) {
        const int n = n0 + wn * 64 + ct * 16 + l15;
        const float bias = bffn[(size_t)layer * DM + n];
#pragma unroll
        for (int rt = 0; rt < 2; ++rt)
#pragma unroll
            for (int r = 0; r < 4; ++r) {
                const int m = m0 + wm * 32 + rt * 16 + quad * 4 + r;
                R[(size_t)m * DM + n] = fmaxf(acc[rt][ct][r] + bias, 0.f);
            }
    }
}

// ---------------- X = (X+R - mu) / var  (divide by VARIANCE — faithful bug) ----------------
__global__ __launch_bounds__(256) void add_ln(
    const float* __restrict__ Xin, const float* __restrict__ Rr,
    float* __restrict__ Xout, __hip_bfloat16* __restrict__ Xh)
{
    __shared__ float red[8];
    const int t = threadIdx.x;
    const size_t base = (size_t)blockIdx.x * DM;
    float4 x4 = *(const float4*)&Xin[base + t * 4];
    float4 r4 = *(const float4*)&Rr[base + t * 4];
    float v[4] = {x4.x + r4.x, x4.y + r4.y, x4.z + r4.z, x4.w + r4.w};
    float ssum = wave_sum(v[0] + v[1] + v[2] + v[3]);
    if ((t & 63) == 0) red[t >> 6] = ssum;
    __syncthreads();
    const float mu = (red[0] + red[1] + red[2] + red[3]) * (1.f / DM);
    float sq = 0.f;
#pragma unroll
    for (int i = 0; i < 4; ++i) { const float d = v[i] - mu; sq = fmaf(d, d, sq); }
    sq = wave_sum(sq);
    if ((t & 63) == 0) red[4 + (t >> 6)] = sq;
    __syncthreads();
    const float var = (red[4] + red[5] + red[6] + red[7]) * (1.f / DM);
    const float inv = 1.f / var;
    float4 o = {(v[0] - mu) * inv, (v[1] - mu) * inv, (v[2] - mu) * inv, (v[3] - mu) * inv};
    *(float4*)&Xout[base + t * 4] = o;
    union { short s[4]; float2 f2; } hb;
    hb.s[0] = f2bf(o.x); hb.s[1] = f2bf(o.y); hb.s[2] = f2bf(o.z); hb.s[3] = f2bf(o.w);
    *(float2*)&Xh[base + t * 4] = hb.f2;
}

// ---------------- last-token logits, both batches in one pass over Wout ----------------
__global__ __launch_bounds__(256) void last_logits2(
    const float* __restrict__ X, const float* __restrict__ Wout,
    const float* __restrict__ bout, float* __restrict__ logits)
{
    __shared__ float xs[2 * DM];
    const int t = threadIdx.x;
    for (int k = t; k < 2 * DM; k += 256) {
        const int bb = k >> 10, d = k & (DM - 1);
        xs[k] = X[((size_t)bb * NS + NS - 1) * DM + d];
    }
    __syncthreads();
    const int v = blockIdx.x * 256 + t;
    float a0 = bout[v], a1 = a0;
    for (int d = 0; d < DM; ++d) {
        const float w = Wout[(size_t)d * NV + v];   // coalesced; Wout read ONCE
        a0 = fmaf(xs[d], w, a0);
        a1 = fmaf(xs[DM + d], w, a1);
    }
    logits[v] = a0;
    logits[NV + v] = a1;
}

__global__ __launch_bounds__(256) void final_softmax(
    const float* __restrict__ logits, float* __restrict__ out)
{
    __shared__ float red[8];
    const int b = blockIdx.x, t = threadIdx.x;
    const float* lp = logits + b * NV;
    float mx = -1e30f;
    for (int v = t; v < NV; v += 256) mx = fmaxf(mx, lp[v]);
    mx = wave_max(mx);
    if ((t & 63) == 0) red[t >> 6] = mx;
    __syncthreads();
    mx = fmaxf(fmaxf(red[0], red[1]), fmaxf(red[2], red[3]));
    float sum = 0.f;
    for (int v = t; v < NV; v += 256) sum += __expf(lp[v] - mx);
    sum = wave_sum(sum);
    if ((t & 63) == 0) red[4 + (t >> 6)] = sum;
    __syncthreads();
    sum = red[4] + red[5] + red[6] + red[7];
    const float inv = 1.f / sum;
    for (int v = t; v < NV; v += 256) out[b * NV + v] = __expf(lp[v] - mx) * inv;
}

extern "C" void kernel_launch(void* const* d_in, const int* in_sizes, int n_in,
                              void* d_out, int out_size, void* d_ws, size_t ws_size,
                              hipStream_t stream)
{
    (void)in_sizes; (void)n_in; (void)out_size; (void)ws_size;
    const float* X_in = (const float*)d_in[0];
    const float* Wq   = (const float*)d_in[1];
    const float* Wk   = (const float*)d_in[2];
    const float* Wv   = (const float*)d_in[3];
    const float* bq   = (const float*)d_in[4];
    const float* bk   = (const float*)d_in[5];
    const float* bv   = (const float*)d_in[6];
    const float* Wffn = (const float*)d_in[7];
    const float* bffn = (const float*)d_in[8];
    const float* Wout = (const float*)d_in[9];
    const float* bout = (const float*)d_in[10];
    float* out = (float*)d_out;

    // workspace carve-up (~101 MB)
    const size_t NE = (size_t)NM * DM;
    char* p = (char*)d_ws;
    float* Xb = (float*)p;                    p += NE * 4;
    float* Rb = (float*)p;                    p += NE * 4;
    float* logits = (float*)p;                p += (size_t)NB * NV * 4;
    __hip_bfloat16* Xhi  = (__hip_bfloat16*)p; p += NE * 2;
    __hip_bfloat16* Qb   = (__hip_bfloat16*)p; p += NE * 2;
    __hip_bfloat16* Kb   = (__hip_bfloat16*)p; p += NE * 2;
    __hip_bfloat16* Vtb  = (__hip_bfloat16*)p; p += NE * 2;
    __hip_bfloat16* WqkvT = (__hip_bfloat16*)p; p += (size_t)3 * 64 * 64 * DM * 2;
    __hip_bfloat16* WffnT = (__hip_bfloat16*)p; p += (size_t)NL * DM * DM * 2;

    wqkv_transpose<<<dim3(16, 192), 256, 0, stream>>>(Wq, Wk, Wv, WqkvT);
    wffn_transpose<<<dim3(16, 16, NL), 256, 0, stream>>>(Wffn, WffnT);
    convert_x0<<<NM, 256, 0, stream>>>(X_in, Xhi);

    for (int l = 0; l < NL; ++l) {
        const float* Xcur = (l == 0) ? X_in : Xb;   // never write d_in
        qkv_gemm<<<dim3(32, 16), 256, 0, stream>>>(Xhi, WqkvT, bq, bk, bv, Qb, Kb, Vtb, l);
        attn_kernel<<<dim3(32, 16), 512, 0, stream>>>(Qb, Kb, Vtb, Rb);
        add_ln<<<NM, 256, 0, stream>>>(Xcur, Rb, Xb, Xhi);
        ffn_gemm<<<dim3(64, 8), 256, 0, stream>>>(Xhi, WffnT, bffn, Rb, l);
        add_ln<<<NM, 256, 0, stream>>>(Xb, Rb, Xb, Xhi);
    }
    last_logits2<<<NV / 256, 256, 0, stream>>>(Xb, Wout, bout, logits);
    final_softmax<<<NB, 256, 0, stream>>>(logits, out);
}